// Round 6
// baseline (68.548 us; speedup 1.0000x reference)
//
#include <hip/hip_runtime.h>
#include <hip/hip_bf16.h>
#include <stdint.h>

typedef __attribute__((ext_vector_type(8))) short bf16x8;
typedef __attribute__((ext_vector_type(4))) float f32x4;

__device__ __forceinline__ unsigned short f2bf(float f) {
  union { float f; uint32_t u; } v; v.f = f;
  uint32_t u = v.u;
  return (unsigned short)((u + 0x7fffu + ((u >> 16) & 1u)) >> 16);
}
__device__ __forceinline__ float bf2f(unsigned short h) {
  union { uint32_t u; float f; } v; v.u = ((uint32_t)h) << 16;
  return v.f;
}

#define GLL(g, l) __builtin_amdgcn_global_load_lds( \
    (const __attribute__((address_space(1))) void*)(g), \
    (__attribute__((address_space(3))) void*)(l), 16, 0, 0)

// ---------------- QKV projection GEMM, fused fp32->bf16 convert ----------------
// C[m,n] = x[m,:]·W[n,:] + b[n]. 64x128 tile, BK=64, 4 waves (2m x 2n), dbuf LDS,
// reg-staged global->LDS (T14: loads for kt+1 issued before MFMAs on kt).
// Panel by: 0->Wk/kb, 1->Wq/qtb(transposed), 2..5->Wv/vb+vtb.
__global__ __launch_bounds__(256, 3) void qkv_gemm(
    const float* __restrict__ x,
    const float* __restrict__ wk, const float* __restrict__ wq, const float* __restrict__ wv,
    const float* __restrict__ pbk, const float* __restrict__ pbq, const float* __restrict__ pbv,
    unsigned short* __restrict__ kb, unsigned short* __restrict__ qtb,
    unsigned short* __restrict__ vb, unsigned short* __restrict__ vtb)
{
  __shared__ unsigned short Alds[2][64 * 64];
  __shared__ unsigned short Blds[2][128 * 64];
  const int tid = threadIdx.x;
  const int lane = tid & 63;
  const int wid = tid >> 6;
  const int wm = wid >> 1, wn = wid & 1;
  // bijective XCD-chunk swizzle: 768 blocks = 8 XCDs x 96 contiguous
  const int wg = blockIdx.x;
  const int s = (wg & 7) * 96 + (wg >> 3);
  const int bx = s & 127, by = s >> 7;       // bx: m-tile 0..127, by: n-panel 0..5
  const int m0 = bx * 64;
  const int l15 = lane & 15, l4 = lane >> 4;

  const float* wsrc; const float* bsrc; int nrow0;
  if (by == 0)      { wsrc = wk; bsrc = pbk; nrow0 = 0; }
  else if (by == 1) { wsrc = wq; bsrc = pbq; nrow0 = 0; }
  else              { wsrc = wv; bsrc = pbv; nrow0 = (by - 2) * 128; }

  f32x4 acc[2][4] = {};
  float4 ra[4], rb[8];   // staged fp32 halves (16B each)

  auto loadregs = [&](int kt) {
    const int k0 = kt * 64;
    #pragma unroll
    for (int p = 0; p < 4; ++p) {              // A: 64 rows x 16 halves
      const int h = p * 256 + tid;
      const int row = h >> 4, hw = h & 15;
      ra[p] = *(const float4*)(x + (size_t)(m0 + row) * 512 + k0 + hw * 4);
    }
    #pragma unroll
    for (int p = 0; p < 8; ++p) {              // B: 128 rows x 16 halves
      const int h = p * 256 + tid;
      const int row = h >> 4, hw = h & 15;
      rb[p] = *(const float4*)(wsrc + (size_t)(nrow0 + row) * 512 + k0 + hw * 4);
    }
  };
  auto cvtwrite = [&](int b) {
    #pragma unroll
    for (int p = 0; p < 4; ++p) {
      const int h = p * 256 + tid;
      const int row = h >> 4, hw = h & 15;
      const int ci = hw >> 1, part = hw & 1;
      ushort4 o; o.x = f2bf(ra[p].x); o.y = f2bf(ra[p].y); o.z = f2bf(ra[p].z); o.w = f2bf(ra[p].w);
      *(ushort4*)((char*)&Alds[b][0] + row * 128 + ((ci ^ (row & 7)) * 16) + part * 8) = o;
    }
    #pragma unroll
    for (int p = 0; p < 8; ++p) {
      const int h = p * 256 + tid;
      const int row = h >> 4, hw = h & 15;
      const int ci = hw >> 1, part = hw & 1;
      ushort4 o; o.x = f2bf(rb[p].x); o.y = f2bf(rb[p].y); o.z = f2bf(rb[p].z); o.w = f2bf(rb[p].w);
      *(ushort4*)((char*)&Blds[b][0] + row * 128 + ((ci ^ (row & 7)) * 16) + part * 8) = o;
    }
  };

  loadregs(0);
  cvtwrite(0);
  __syncthreads();

  for (int kt = 0; kt < 8; ++kt) {
    const int cur = kt & 1;
    if (kt < 7) loadregs(kt + 1);      // issue next-tile loads; latency hides under MFMAs
    #pragma unroll
    for (int kk = 0; kk < 2; ++kk) {
      bf16x8 af[2], bfv[4];
      #pragma unroll
      for (int i = 0; i < 2; ++i) {
        const int ra_ = wm * 32 + i * 16 + l15;
        const int c  = kk * 4 + l4;
        af[i] = *(const bf16x8*)(&Alds[cur][ra_ * 64 + ((c ^ (ra_ & 7)) * 8)]);
      }
      #pragma unroll
      for (int j = 0; j < 4; ++j) {
        const int rb_ = wn * 64 + j * 16 + l15;
        const int c  = kk * 4 + l4;
        bfv[j] = *(const bf16x8*)(&Blds[cur][rb_ * 64 + ((c ^ (rb_ & 7)) * 8)]);
      }
      #pragma unroll
      for (int i = 0; i < 2; ++i)
        #pragma unroll
        for (int j = 0; j < 4; ++j)
          acc[i][j] = __builtin_amdgcn_mfma_f32_16x16x32_bf16(af[i], bfv[j], acc[i][j], 0, 0, 0);
    }
    if (kt < 7) cvtwrite(cur ^ 1);     // waits vmcnt, converts, fills back buffer
    __syncthreads();
  }

  #pragma unroll
  for (int i = 0; i < 2; ++i) {
    #pragma unroll
    for (int j = 0; j < 4; ++j) {
      const int rbase = m0 + wm * 32 + i * 16 + l4 * 4;
      const int c = wn * 64 + j * 16 + l15;        // panel-local col 0..127
      const float bias = bsrc[nrow0 + c];
      unsigned short o[4];
      #pragma unroll
      for (int r = 0; r < 4; ++r) o[r] = f2bf(acc[i][j][r] + bias);
      if (by == 0) {
        #pragma unroll
        for (int r = 0; r < 4; ++r) kb[(size_t)(rbase + r) * 128 + c] = o[r];
      } else if (by == 1) {
        ushort4 t; t.x = o[0]; t.y = o[1]; t.z = o[2]; t.w = o[3];
        *(ushort4*)(qtb + (size_t)c * 8192 + rbase) = t;
      } else {
        const int vcol = nrow0 + c;
        #pragma unroll
        for (int r = 0; r < 4; ++r) vb[(size_t)(rbase + r) * 512 + vcol] = o[r];
        ushort4 t; t.x = o[0]; t.y = o[1]; t.z = o[2]; t.w = o[3];
        *(ushort4*)(vtb + (size_t)vcol * 8192 + rbase) = t;
      }
    }
  }
}

// ---------------- [G|H] = Q^T [Q|V]  (LDS-staged split-K, double-buffered) ----------------
// grid (kc=32 g-chunks of 256, nq=8 col-slices of 80), 512 thr (8 waves).
__global__ __launch_bounds__(512) void gh_gemm(
    const unsigned short* __restrict__ qtb, const unsigned short* __restrict__ vtb,
    unsigned short* __restrict__ pb)
{
  __shared__ unsigned short Alds[2][128 * 64];  // [m][g] swizzled
  __shared__ unsigned short Blds[2][80 * 64];   // [col][g] swizzled
  const int tid = threadIdx.x, lane = tid & 63, wid = tid >> 6;
  const int l15 = lane & 15, l4 = lane >> 4;
  const int kc = blockIdx.x, nq = blockIdx.y;
  const int g0 = kc * 256;
  const int m0 = wid * 16;

  f32x4 acc[5] = {};

  auto stage = [&](int b, int st) {
    const int gs = g0 + st * 64;
    #pragma unroll
    for (int p = 0; p < 2; ++p) {
      const int e = p * 512 + tid;
      const int row = e >> 3;
      const int cs = (e & 7) ^ (row & 7);
      GLL(qtb + (size_t)row * 8192 + gs + cs * 8, &Alds[b][(p * 512 + (tid & ~63)) * 8]);
    }
    {
      const int row = tid >> 3;
      const int cglob = nq * 80 + row;
      const unsigned short* src = (cglob < 128) ? (qtb + (size_t)cglob * 8192)
                                                : (vtb + (size_t)(cglob - 128) * 8192);
      const int cs = (tid & 7) ^ (row & 7);
      GLL(src + gs + cs * 8, &Blds[b][(tid & ~63) * 8]);
    }
    if (tid < 128) {
      const int e = 512 + tid;
      const int row = e >> 3;
      const int cglob = nq * 80 + row;
      const unsigned short* src = (cglob < 128) ? (qtb + (size_t)cglob * 8192)
                                                : (vtb + (size_t)(cglob - 128) * 8192);
      const int cs = (e & 7) ^ (row & 7);
      GLL(src + gs + cs * 8, &Blds[b][(512 + (tid & ~63)) * 8]);
    }
  };

  stage(0, 0);
  __syncthreads();

  for (int st = 0; st < 4; ++st) {
    const int cur = st & 1;
    if (st < 3) stage(cur ^ 1, st + 1);
    #pragma unroll
    for (int ks = 0; ks < 2; ++ks) {
      const int ra = m0 + l15;
      const int ca = ks * 4 + l4;
      const bf16x8 af = *(const bf16x8*)(&Alds[cur][ra * 64 + ((ca ^ (ra & 7)) * 8)]);
      #pragma unroll
      for (int nf = 0; nf < 5; ++nf) {
        const int rb = nf * 16 + l15;
        const bf16x8 bf = *(const bf16x8*)(&Blds[cur][rb * 64 + ((ca ^ (rb & 7)) * 8)]);
        acc[nf] = __builtin_amdgcn_mfma_f32_16x16x32_bf16(af, bf, acc[nf], 0, 0, 0);
      }
    }
    __syncthreads();
  }

  #pragma unroll
  for (int nf = 0; nf < 5; ++nf) {
    const int col = nq * 80 + nf * 16 + l15;
    #pragma unroll
    for (int r = 0; r < 4; ++r) {
      const int row = m0 + l4 * 4 + r;
      pb[((size_t)kc * 128 + row) * 640 + col] = f2bf(acc[nf][r]);
    }
  }
}

// Sum 32 bf16 partials -> Gb [128][128] bf16, Hbt [512][128] bf16 (H transposed).
__global__ void gh_finalize(const unsigned short* __restrict__ pb,
                            unsigned short* __restrict__ Gb, unsigned short* __restrict__ Hbt) {
  const int idx = blockIdx.x * 256 + threadIdx.x;  // 0..81919
  float s = 0.f;
  #pragma unroll
  for (int p = 0; p < 32; ++p) s += bf2f(pb[(size_t)p * 81920 + idx]);
  const int m = idx / 640, c = idx % 640;
  if (c < 128) Gb[m * 128 + c] = f2bf(s);
  else         Hbt[(size_t)(c - 128) * 128 + m] = f2bf(s);
}

// ---------------- fused: rnorm (k_i G k_i^T) + out = (K·H)*rnorm + v ----------------
// grid 512 blocks of 16 rows; 512 thr (8 waves). Barrier deferred until after U-MFMAs.
__global__ __launch_bounds__(512) void tnorm_uv(
    const unsigned short* __restrict__ kb, const unsigned short* __restrict__ Gb,
    const unsigned short* __restrict__ Hbt, const unsigned short* __restrict__ vb,
    float* __restrict__ out)
{
  __shared__ float ssq_part[8][16];
  __shared__ float rnorm_lds[16];
  const int tid = threadIdx.x, lane = tid & 63, wid = tid >> 6;
  const int l15 = lane & 15, l4 = lane >> 4;
  const int rowbase = blockIdx.x * 16;

  // K A-fragments for these 16 rows (shared by both phases)
  bf16x8 af[4];
  #pragma unroll
  for (int ks = 0; ks < 4; ++ks)
    af[ks] = *(const bf16x8*)(kb + (size_t)(rowbase + l15) * 128 + ks * 32 + l4 * 8);

  // ---- phase 1: T-frag (cols wid*16..+16) of T = K·G, partial rowdot ----
  f32x4 tac = {};
  #pragma unroll
  for (int ks = 0; ks < 4; ++ks) {
    const bf16x8 bf = *(const bf16x8*)(Gb + (size_t)(wid * 16 + l15) * 128 + ks * 32 + l4 * 8);
    tac = __builtin_amdgcn_mfma_f32_16x16x32_bf16(af[ks], bf, tac, 0, 0, 0);
  }
  float ssq[4];
  #pragma unroll
  for (int r = 0; r < 4; ++r) {
    const int row = rowbase + l4 * 4 + r;
    ssq[r] = tac[r] * bf2f(kb[(size_t)row * 128 + wid * 16 + l15]);
  }
  #pragma unroll
  for (int d = 1; d < 16; d <<= 1)
    #pragma unroll
    for (int r = 0; r < 4; ++r) ssq[r] += __shfl_xor(ssq[r], d);
  if (l15 == 0) {
    #pragma unroll
    for (int r = 0; r < 4; ++r) ssq_part[wid][l4 * 4 + r] = ssq[r];
  }

  // ---- phase 2 (before barrier): U = K·H for cols [wid*64, +64) ----
  f32x4 acc[4] = {};
  #pragma unroll
  for (int ks = 0; ks < 4; ++ks) {
    #pragma unroll
    for (int nf = 0; nf < 4; ++nf) {
      const int col = wid * 64 + nf * 16 + l15;
      const bf16x8 bf = *(const bf16x8*)(Hbt + (size_t)col * 128 + ks * 32 + l4 * 8);
      acc[nf] = __builtin_amdgcn_mfma_f32_16x16x32_bf16(af[ks], bf, acc[nf], 0, 0, 0);
    }
  }
  // hoist residual loads so they pipeline under the barrier
  float vres[4][4];
  #pragma unroll
  for (int nf = 0; nf < 4; ++nf) {
    const int col = wid * 64 + nf * 16 + l15;
    #pragma unroll
    for (int r = 0; r < 4; ++r)
      vres[nf][r] = bf2f(vb[(size_t)(rowbase + l4 * 4 + r) * 512 + col]);
  }

  __syncthreads();
  if (tid < 16) {
    float s = 0.f;
    #pragma unroll
    for (int w = 0; w < 8; ++w) s += ssq_part[w][tid];
    rnorm_lds[tid] = 1.0f / fmaxf(sqrtf(s), 1e-12f);
  }
  __syncthreads();

  float rn[4];
  #pragma unroll
  for (int r = 0; r < 4; ++r) rn[r] = rnorm_lds[l4 * 4 + r];

  #pragma unroll
  for (int nf = 0; nf < 4; ++nf) {
    const int col = wid * 64 + nf * 16 + l15;
    #pragma unroll
    for (int r = 0; r < 4; ++r) {
      const int row = rowbase + l4 * 4 + r;
      out[(size_t)row * 512 + col] = acc[nf][r] * rn[r] + vres[nf][r];
    }
  }
}

extern "C" void kernel_launch(void* const* d_in, const int* in_sizes, int n_in,
                              void* d_out, int out_size, void* d_ws, size_t ws_size,
                              hipStream_t stream) {
  const float* x  = (const float*)d_in[0];
  const float* Wk = (const float*)d_in[1];
  const float* bk = (const float*)d_in[2];
  const float* Wq = (const float*)d_in[3];
  const float* bq = (const float*)d_in[4];
  const float* Wv = (const float*)d_in[5];
  const float* bv = (const float*)d_in[6];
  float* out = (float*)d_out;

  char* ws = (char*)d_ws;
  unsigned short* kb   = (unsigned short*)(ws);              //  8192*128*2 = 2,097,152
  unsigned short* vb   = (unsigned short*)(ws + 2097152);    //  8192*512*2 = 8,388,608
  unsigned short* vtb  = (unsigned short*)(ws + 10485760);   //   512*8192*2= 8,388,608
  unsigned short* qtb  = (unsigned short*)(ws + 18874368);   //   128*8192*2= 2,097,152
  unsigned short* pb   = (unsigned short*)(ws + 20971520);   //  32*128*640*2=5,242,880
  unsigned short* Gb   = (unsigned short*)(ws + 26214400);   //   128*128*2 =    32,768
  unsigned short* Hbt  = (unsigned short*)(ws + 26247168);   //   512*128*2 =   131,072

  qkv_gemm<<<768, 256, 0, stream>>>(x, Wk, Wq, Wv, bk, bq, bv, kb, qtb, vb, vtb);
  gh_gemm<<<dim3(32, 8), 512, 0, stream>>>(qtb, vtb, pb);
  gh_finalize<<<320, 256, 0, stream>>>(pb, Gb, Hbt);
  tnorm_uv<<<512, 512, 0, stream>>>(kb, Gb, Hbt, vb, out);
}

// Round 7
// 56.249 us; speedup vs baseline: 1.2186x; 1.2186x over previous
//
#include <hip/hip_runtime.h>
#include <hip/hip_bf16.h>
#include <stdint.h>

typedef __attribute__((ext_vector_type(8))) short bf16x8;
typedef __attribute__((ext_vector_type(4))) float f32x4;

__device__ __forceinline__ unsigned short f2bf(float f) {
  union { float f; uint32_t u; } v; v.f = f;
  uint32_t u = v.u;
  return (unsigned short)((u + 0x7fffu + ((u >> 16) & 1u)) >> 16);
}
__device__ __forceinline__ float bf2f(unsigned short h) {
  union { uint32_t u; float f; } v; v.u = ((uint32_t)h) << 16;
  return v.f;
}

#define GLL(g, l) __builtin_amdgcn_global_load_lds( \
    (const __attribute__((address_space(1))) void*)(g), \
    (__attribute__((address_space(3))) void*)(l), 16, 0, 0)

// ---------------- fp32 -> bf16 convert (x and Wk|Wq|Wv in one launch) ----------------
__global__ void cvt_all(const float* __restrict__ x,
                        const float* __restrict__ wk, const float* __restrict__ wq,
                        const float* __restrict__ wv,
                        unsigned short* __restrict__ xb, unsigned short* __restrict__ wb) {
  const int i = (blockIdx.x * 256 + threadIdx.x) * 4;
  const float* src; unsigned short* dst; int off;
  if (i < 4194304) { src = x; dst = xb; off = i; }
  else {
    const int j = i - 4194304;
    if (j < 65536)       { src = wk; off = j; }
    else if (j < 131072) { src = wq; off = j - 65536; }
    else                 { src = wv; off = j - 131072; }
    dst = wb + (j - off);
  }
  const float4 v = *(const float4*)(src + off);
  ushort4 o; o.x = f2bf(v.x); o.y = f2bf(v.y); o.z = f2bf(v.z); o.w = f2bf(v.w);
  *(ushort4*)(dst + off) = o;
}

// ---------------- QKV projection GEMM: C[m,n] = x[m,:]·W[n,:] + b[n] ----------------
// 128x192 tile -> grid exactly 256 blocks (1/CU). BK=64, 512 thr, 8 waves (2m x 4n),
// wave = 64x48 (acc 4x3). Double-buffered GLL staging (80 KB LDS).
__global__ __launch_bounds__(512, 2) void qkv_gemm(
    const unsigned short* __restrict__ xb, const unsigned short* __restrict__ wb,
    const float* __restrict__ pbk, const float* __restrict__ pbq, const float* __restrict__ pbv,
    unsigned short* __restrict__ kb, unsigned short* __restrict__ qtb,
    unsigned short* __restrict__ vb, unsigned short* __restrict__ vtb)
{
  __shared__ unsigned short Alds[2][128 * 64];   // [m][k] swizzled
  __shared__ unsigned short Blds[2][192 * 64];   // [n][k] swizzled
  const int tid = threadIdx.x;
  const int lane = tid & 63;
  const int wid = tid >> 6;
  const int wm = wid >> 2, wn = wid & 3;
  // bijective XCD-chunk swizzle: 256 blocks = 8 XCDs x 32 contiguous
  const int wg = blockIdx.x;
  const int s = (wg & 7) * 32 + (wg >> 3);
  const int m0 = (s & 63) * 128;                 // 64 row-tiles
  const int n0 = (s >> 6) * 192;                 // 4 col-panels
  const int l15 = lane & 15, l4 = lane >> 4;

  f32x4 acc[4][3] = {};

  auto stage = [&](int b, int kt) {
    const int k0 = kt * 64;
    #pragma unroll
    for (int p = 0; p < 2; ++p) {                // A: 128 rows x 8 chunks
      const int e = p * 512 + tid;
      const int row = e >> 3;
      const int cs = (e & 7) ^ (row & 7);
      GLL(xb + (size_t)(m0 + row) * 512 + k0 + cs * 8, &Alds[b][(p * 512 + (tid & ~63)) * 8]);
    }
    #pragma unroll
    for (int p = 0; p < 3; ++p) {                // B: 192 rows x 8 chunks
      const int e = p * 512 + tid;
      const int row = e >> 3;
      const int cs = (e & 7) ^ (row & 7);
      GLL(wb + (size_t)(n0 + row) * 512 + k0 + cs * 8, &Blds[b][(p * 512 + (tid & ~63)) * 8]);
    }
  };

  stage(0, 0);
  __syncthreads();

  for (int kt = 0; kt < 8; ++kt) {
    const int cur = kt & 1;
    if (kt < 7) stage(cur ^ 1, kt + 1);  // async loads overlap compute below
    #pragma unroll
    for (int kk = 0; kk < 2; ++kk) {
      bf16x8 af[4], bfv[3];
      const int c = kk * 4 + l4;
      #pragma unroll
      for (int i = 0; i < 4; ++i) {
        const int ra = wm * 64 + i * 16 + l15;
        af[i] = *(const bf16x8*)(&Alds[cur][ra * 64 + ((c ^ (ra & 7)) * 8)]);
      }
      #pragma unroll
      for (int j = 0; j < 3; ++j) {
        const int rb = wn * 48 + j * 16 + l15;
        bfv[j] = *(const bf16x8*)(&Blds[cur][rb * 64 + ((c ^ (rb & 7)) * 8)]);
      }
      #pragma unroll
      for (int i = 0; i < 4; ++i)
        #pragma unroll
        for (int j = 0; j < 3; ++j)
          acc[i][j] = __builtin_amdgcn_mfma_f32_16x16x32_bf16(af[i], bfv[j], acc[i][j], 0, 0, 0);
    }
    __syncthreads();
  }

  #pragma unroll
  for (int i = 0; i < 4; ++i) {
    #pragma unroll
    for (int j = 0; j < 3; ++j) {
      const int rbase = m0 + wm * 64 + i * 16 + l4 * 4;
      const int c = n0 + wn * 48 + j * 16 + l15;   // global col 0..767
      const float bias = (c < 128) ? pbk[c] : (c < 256) ? pbq[c - 128] : pbv[c - 256];
      unsigned short o[4];
      #pragma unroll
      for (int r = 0; r < 4; ++r) o[r] = f2bf(acc[i][j][r] + bias);
      if (c < 128) {
        #pragma unroll
        for (int r = 0; r < 4; ++r) kb[(size_t)(rbase + r) * 128 + c] = o[r];
      } else if (c < 256) {
        ushort4 t; t.x = o[0]; t.y = o[1]; t.z = o[2]; t.w = o[3];
        *(ushort4*)(qtb + (size_t)(c - 128) * 8192 + rbase) = t;
      } else {
        const int vcol = c - 256;
        #pragma unroll
        for (int r = 0; r < 4; ++r) vb[(size_t)(rbase + r) * 512 + vcol] = o[r];
        ushort4 t; t.x = o[0]; t.y = o[1]; t.z = o[2]; t.w = o[3];
        *(ushort4*)(vtb + (size_t)vcol * 8192 + rbase) = t;
      }
    }
  }
}

// ---------------- [G|H] = Q^T [Q|V]  (LDS-staged split-K, double-buffered) ----------------
// grid (kc=32 g-chunks of 256, nq=8 col-slices of 80), 512 thr (8 waves).
__global__ __launch_bounds__(512) void gh_gemm(
    const unsigned short* __restrict__ qtb, const unsigned short* __restrict__ vtb,
    unsigned short* __restrict__ pb)
{
  __shared__ unsigned short Alds[2][128 * 64];  // [m][g] swizzled
  __shared__ unsigned short Blds[2][80 * 64];   // [col][g] swizzled
  const int tid = threadIdx.x, lane = tid & 63, wid = tid >> 6;
  const int l15 = lane & 15, l4 = lane >> 4;
  const int kc = blockIdx.x, nq = blockIdx.y;
  const int g0 = kc * 256;
  const int m0 = wid * 16;

  f32x4 acc[5] = {};

  auto stage = [&](int b, int st) {
    const int gs = g0 + st * 64;
    #pragma unroll
    for (int p = 0; p < 2; ++p) {
      const int e = p * 512 + tid;
      const int row = e >> 3;
      const int cs = (e & 7) ^ (row & 7);
      GLL(qtb + (size_t)row * 8192 + gs + cs * 8, &Alds[b][(p * 512 + (tid & ~63)) * 8]);
    }
    {
      const int row = tid >> 3;
      const int cglob = nq * 80 + row;
      const unsigned short* src = (cglob < 128) ? (qtb + (size_t)cglob * 8192)
                                                : (vtb + (size_t)(cglob - 128) * 8192);
      const int cs = (tid & 7) ^ (row & 7);
      GLL(src + gs + cs * 8, &Blds[b][(tid & ~63) * 8]);
    }
    if (tid < 128) {
      const int e = 512 + tid;
      const int row = e >> 3;
      const int cglob = nq * 80 + row;
      const unsigned short* src = (cglob < 128) ? (qtb + (size_t)cglob * 8192)
                                                : (vtb + (size_t)(cglob - 128) * 8192);
      const int cs = (e & 7) ^ (row & 7);
      GLL(src + gs + cs * 8, &Blds[b][(512 + (tid & ~63)) * 8]);
    }
  };

  stage(0, 0);
  __syncthreads();

  for (int st = 0; st < 4; ++st) {
    const int cur = st & 1;
    if (st < 3) stage(cur ^ 1, st + 1);
    #pragma unroll
    for (int ks = 0; ks < 2; ++ks) {
      const int ra = m0 + l15;
      const int ca = ks * 4 + l4;
      const bf16x8 af = *(const bf16x8*)(&Alds[cur][ra * 64 + ((ca ^ (ra & 7)) * 8)]);
      #pragma unroll
      for (int nf = 0; nf < 5; ++nf) {
        const int rb = nf * 16 + l15;
        const bf16x8 bf = *(const bf16x8*)(&Blds[cur][rb * 64 + ((ca ^ (rb & 7)) * 8)]);
        acc[nf] = __builtin_amdgcn_mfma_f32_16x16x32_bf16(af, bf, acc[nf], 0, 0, 0);
      }
    }
    __syncthreads();
  }

  #pragma unroll
  for (int nf = 0; nf < 5; ++nf) {
    const int col = nq * 80 + nf * 16 + l15;
    #pragma unroll
    for (int r = 0; r < 4; ++r) {
      const int row = m0 + l4 * 4 + r;
      pb[((size_t)kc * 128 + row) * 640 + col] = f2bf(acc[nf][r]);
    }
  }
}

// Sum 32 bf16 partials -> Gb [128][128] bf16, Hbt [512][128] bf16 (H transposed).
__global__ void gh_finalize(const unsigned short* __restrict__ pb,
                            unsigned short* __restrict__ Gb, unsigned short* __restrict__ Hbt) {
  const int idx = blockIdx.x * 256 + threadIdx.x;  // 0..81919
  float s = 0.f;
  #pragma unroll
  for (int p = 0; p < 32; ++p) s += bf2f(pb[(size_t)p * 81920 + idx]);
  const int m = idx / 640, c = idx % 640;
  if (c < 128) Gb[m * 128 + c] = f2bf(s);
  else         Hbt[(size_t)(c - 128) * 128 + m] = f2bf(s);
}

// ---------------- fused: rnorm (k_i G k_i^T) + out = (K·H)*rnorm + v ----------------
// grid 512 blocks of 16 rows; 512 thr (8 waves). Barrier deferred until after U-MFMAs.
__global__ __launch_bounds__(512) void tnorm_uv(
    const unsigned short* __restrict__ kb, const unsigned short* __restrict__ Gb,
    const unsigned short* __restrict__ Hbt, const unsigned short* __restrict__ vb,
    float* __restrict__ out)
{
  __shared__ float ssq_part[8][16];
  __shared__ float rnorm_lds[16];
  const int tid = threadIdx.x, lane = tid & 63, wid = tid >> 6;
  const int l15 = lane & 15, l4 = lane >> 4;
  const int rowbase = blockIdx.x * 16;

  // K A-fragments for these 16 rows (shared by both phases)
  bf16x8 af[4];
  #pragma unroll
  for (int ks = 0; ks < 4; ++ks)
    af[ks] = *(const bf16x8*)(kb + (size_t)(rowbase + l15) * 128 + ks * 32 + l4 * 8);

  // ---- phase 1: T-frag (cols wid*16..+16) of T = K·G, partial rowdot ----
  f32x4 tac = {};
  #pragma unroll
  for (int ks = 0; ks < 4; ++ks) {
    const bf16x8 bf = *(const bf16x8*)(Gb + (size_t)(wid * 16 + l15) * 128 + ks * 32 + l4 * 8);
    tac = __builtin_amdgcn_mfma_f32_16x16x32_bf16(af[ks], bf, tac, 0, 0, 0);
  }
  float ssq[4];
  #pragma unroll
  for (int r = 0; r < 4; ++r) {
    const int row = rowbase + l4 * 4 + r;
    ssq[r] = tac[r] * bf2f(kb[(size_t)row * 128 + wid * 16 + l15]);
  }
  #pragma unroll
  for (int d = 1; d < 16; d <<= 1)
    #pragma unroll
    for (int r = 0; r < 4; ++r) ssq[r] += __shfl_xor(ssq[r], d);
  if (l15 == 0) {
    #pragma unroll
    for (int r = 0; r < 4; ++r) ssq_part[wid][l4 * 4 + r] = ssq[r];
  }

  // ---- phase 2 (before barrier): U = K·H for cols [wid*64, +64) ----
  f32x4 acc[4] = {};
  #pragma unroll
  for (int ks = 0; ks < 4; ++ks) {
    #pragma unroll
    for (int nf = 0; nf < 4; ++nf) {
      const int col = wid * 64 + nf * 16 + l15;
      const bf16x8 bf = *(const bf16x8*)(Hbt + (size_t)col * 128 + ks * 32 + l4 * 8);
      acc[nf] = __builtin_amdgcn_mfma_f32_16x16x32_bf16(af[ks], bf, acc[nf], 0, 0, 0);
    }
  }
  // hoist residual loads so they pipeline under the barrier
  float vres[4][4];
  #pragma unroll
  for (int nf = 0; nf < 4; ++nf) {
    const int col = wid * 64 + nf * 16 + l15;
    #pragma unroll
    for (int r = 0; r < 4; ++r)
      vres[nf][r] = bf2f(vb[(size_t)(rowbase + l4 * 4 + r) * 512 + col]);
  }

  __syncthreads();
  if (tid < 16) {
    float s = 0.f;
    #pragma unroll
    for (int w = 0; w < 8; ++w) s += ssq_part[w][tid];
    rnorm_lds[tid] = 1.0f / fmaxf(sqrtf(s), 1e-12f);
  }
  __syncthreads();

  float rn[4];
  #pragma unroll
  for (int r = 0; r < 4; ++r) rn[r] = rnorm_lds[l4 * 4 + r];

  #pragma unroll
  for (int nf = 0; nf < 4; ++nf) {
    const int col = wid * 64 + nf * 16 + l15;
    #pragma unroll
    for (int r = 0; r < 4; ++r) {
      const int row = rowbase + l4 * 4 + r;
      out[(size_t)row * 512 + col] = acc[nf][r] * rn[r] + vres[nf][r];
    }
  }
}

extern "C" void kernel_launch(void* const* d_in, const int* in_sizes, int n_in,
                              void* d_out, int out_size, void* d_ws, size_t ws_size,
                              hipStream_t stream) {
  const float* x  = (const float*)d_in[0];
  const float* Wk = (const float*)d_in[1];
  const float* bk = (const float*)d_in[2];
  const float* Wq = (const float*)d_in[3];
  const float* bq = (const float*)d_in[4];
  const float* Wv = (const float*)d_in[5];
  const float* bv = (const float*)d_in[6];
  float* out = (float*)d_out;

  char* ws = (char*)d_ws;
  unsigned short* xb   = (unsigned short*)(ws);              //  8192*512*2 = 8,388,608
  unsigned short* wb   = (unsigned short*)(ws + 8388608);    //   768*512*2 =   786,432
  unsigned short* kb   = (unsigned short*)(ws + 9175040);    //  8192*128*2 = 2,097,152
  unsigned short* vb   = (unsigned short*)(ws + 11272192);   //  8192*512*2 = 8,388,608
  unsigned short* vtb  = (unsigned short*)(ws + 19660800);   //   512*8192*2= 8,388,608
  unsigned short* qtb  = (unsigned short*)(ws + 28049408);   //   128*8192*2= 2,097,152
  unsigned short* pb   = (unsigned short*)(ws + 30146560);   //  32*128*640*2=5,242,880
  unsigned short* Gb   = (unsigned short*)(ws + 35389440);   //   128*128*2 =    32,768
  unsigned short* Hbt  = (unsigned short*)(ws + 35422208);   //   512*128*2 =   131,072

  cvt_all<<<4480, 256, 0, stream>>>(x, Wk, Wq, Wv, xb, wb);
  qkv_gemm<<<256, 512, 0, stream>>>(xb, wb, bk, bq, bv, kb, qtb, vb, vtb);
  gh_gemm<<<dim3(32, 8), 512, 0, stream>>>(qtb, vtb, pb);
  gh_finalize<<<320, 256, 0, stream>>>(pb, Gb, Hbt);
  tnorm_uv<<<512, 512, 0, stream>>>(kb, Gb, Hbt, vb, out);
}

// Round 8
// 54.991 us; speedup vs baseline: 1.2465x; 1.0229x over previous
//
#include <hip/hip_runtime.h>
#include <hip/hip_bf16.h>
#include <stdint.h>

typedef __attribute__((ext_vector_type(8))) short bf16x8;
typedef __attribute__((ext_vector_type(4))) float f32x4;

__device__ __forceinline__ unsigned short f2bf(float f) {
  union { float f; uint32_t u; } v; v.f = f;
  uint32_t u = v.u;
  return (unsigned short)((u + 0x7fffu + ((u >> 16) & 1u)) >> 16);
}
__device__ __forceinline__ float bf2f(unsigned short h) {
  union { uint32_t u; float f; } v; v.u = ((uint32_t)h) << 16;
  return v.f;
}

#define GLL(g, l) __builtin_amdgcn_global_load_lds( \
    (const __attribute__((address_space(1))) void*)(g), \
    (__attribute__((address_space(3))) void*)(l), 16, 0, 0)
#define WAITV(N) asm volatile("s_waitcnt vmcnt(" #N ")" ::: "memory")
#define SFENCE() __builtin_amdgcn_sched_barrier(0)
#define RBAR()   __builtin_amdgcn_s_barrier()

// ---------------- fp32 -> bf16 convert (x and Wk|Wq|Wv in one launch) ----------------
__global__ void cvt_all(const float* __restrict__ x,
                        const float* __restrict__ wk, const float* __restrict__ wq,
                        const float* __restrict__ wv,
                        unsigned short* __restrict__ xb, unsigned short* __restrict__ wb) {
  const int i = (blockIdx.x * 256 + threadIdx.x) * 4;
  const float* src; unsigned short* dst; int off;
  if (i < 4194304) { src = x; dst = xb; off = i; }
  else {
    const int j = i - 4194304;
    if (j < 65536)       { src = wk; off = j; }
    else if (j < 131072) { src = wq; off = j - 65536; }
    else                 { src = wv; off = j - 131072; }
    dst = wb + (j - off);
  }
  const float4 v = *(const float4*)(src + off);
  ushort4 o; o.x = f2bf(v.x); o.y = f2bf(v.y); o.z = f2bf(v.z); o.w = f2bf(v.w);
  *(ushort4*)(dst + off) = o;
}

// ---------------- QKV projection GEMM: C[m,n] = x[m,:]·W[n,:] + b[n] ----------------
// 128x192 tile -> 256 blocks (1/CU). BK=64, 512 thr, 8 waves (2m x 4n), wave = 64x48.
// Counted-vmcnt 2-ahead pipeline (T4): stage kt+2 issued each step, wait vmcnt(5) not 0.
__global__ __launch_bounds__(512, 2) void qkv_gemm(
    const unsigned short* __restrict__ xb, const unsigned short* __restrict__ wb,
    const float* __restrict__ pbk, const float* __restrict__ pbq, const float* __restrict__ pbv,
    unsigned short* __restrict__ kb, unsigned short* __restrict__ qtb,
    unsigned short* __restrict__ vb, unsigned short* __restrict__ vtb)
{
  __shared__ unsigned short Alds[2][128 * 64];   // [m][k] swizzled
  __shared__ unsigned short Blds[2][192 * 64];   // [n][k] swizzled
  const int tid = threadIdx.x;
  const int lane = tid & 63;
  const int wid = tid >> 6;
  const int wm = wid >> 2, wn = wid & 3;
  const int wg = blockIdx.x;
  const int s = (wg & 7) * 32 + (wg >> 3);       // bijective XCD chunking (256 = 8 x 32)
  const int m0 = (s & 63) * 128;
  const int n0 = (s >> 6) * 192;
  const int l15 = lane & 15, l4 = lane >> 4;

  f32x4 acc[4][3] = {};

  auto stage = [&](int b, int kt) {              // 5 GLL per thread (uniform)
    const int k0 = kt * 64;
    #pragma unroll
    for (int p = 0; p < 2; ++p) {                // A: 128 rows x 8 chunks
      const int e = p * 512 + tid;
      const int row = e >> 3;
      const int cs = (e & 7) ^ (row & 7);
      GLL(xb + (size_t)(m0 + row) * 512 + k0 + cs * 8, &Alds[b][(p * 512 + (tid & ~63)) * 8]);
    }
    #pragma unroll
    for (int p = 0; p < 3; ++p) {                // B: 192 rows x 8 chunks
      const int e = p * 512 + tid;
      const int row = e >> 3;
      const int cs = (e & 7) ^ (row & 7);
      GLL(wb + (size_t)(n0 + row) * 512 + k0 + cs * 8, &Blds[b][(p * 512 + (tid & ~63)) * 8]);
    }
  };

  stage(0, 0);
  stage(1, 1);

  for (int kt = 0; kt < 8; ++kt) {
    const int cur = kt & 1;
    if (kt < 7) { WAITV(5); } else { WAITV(0); }  // stage(kt) landed; stage(kt+1) in flight
    RBAR();
    SFENCE();
    #pragma unroll
    for (int kk = 0; kk < 2; ++kk) {
      bf16x8 af[4], bfv[3];
      const int c = kk * 4 + l4;
      #pragma unroll
      for (int i = 0; i < 4; ++i) {
        const int ra = wm * 64 + i * 16 + l15;
        af[i] = *(const bf16x8*)(&Alds[cur][ra * 64 + ((c ^ (ra & 7)) * 8)]);
      }
      #pragma unroll
      for (int j = 0; j < 3; ++j) {
        const int rb = wn * 48 + j * 16 + l15;
        bfv[j] = *(const bf16x8*)(&Blds[cur][rb * 64 + ((c ^ (rb & 7)) * 8)]);
      }
      #pragma unroll
      for (int i = 0; i < 4; ++i)
        #pragma unroll
        for (int j = 0; j < 3; ++j)
          acc[i][j] = __builtin_amdgcn_mfma_f32_16x16x32_bf16(af[i], bfv[j], acc[i][j], 0, 0, 0);
    }
    SFENCE();
    RBAR();                                      // all waves done reading buf[cur]
    if (kt < 6) stage(cur, kt + 2);              // refill the buffer just freed
  }

  #pragma unroll
  for (int i = 0; i < 4; ++i) {
    #pragma unroll
    for (int j = 0; j < 3; ++j) {
      const int rbase = m0 + wm * 64 + i * 16 + l4 * 4;
      const int c = n0 + wn * 48 + j * 16 + l15;   // global col 0..767
      const float bias = (c < 128) ? pbk[c] : (c < 256) ? pbq[c - 128] : pbv[c - 256];
      unsigned short o[4];
      #pragma unroll
      for (int r = 0; r < 4; ++r) o[r] = f2bf(acc[i][j][r] + bias);
      if (c < 128) {
        #pragma unroll
        for (int r = 0; r < 4; ++r) kb[(size_t)(rbase + r) * 128 + c] = o[r];
      } else if (c < 256) {
        ushort4 t; t.x = o[0]; t.y = o[1]; t.z = o[2]; t.w = o[3];
        *(ushort4*)(qtb + (size_t)(c - 128) * 8192 + rbase) = t;
      } else {
        const int vcol = c - 256;
        #pragma unroll
        for (int r = 0; r < 4; ++r) vb[(size_t)(rbase + r) * 512 + vcol] = o[r];
        ushort4 t; t.x = o[0]; t.y = o[1]; t.z = o[2]; t.w = o[3];
        *(ushort4*)(vtb + (size_t)vcol * 8192 + rbase) = t;
      }
    }
  }
}

// ---------------- [G|H] = Q^T [Q|V]  (LDS-staged split-K, counted-vmcnt pipeline) ----------------
// grid (kc=32 g-chunks of 256, nq=8 col-slices of 80), 512 thr (8 waves).
__global__ __launch_bounds__(512) void gh_gemm(
    const unsigned short* __restrict__ qtb, const unsigned short* __restrict__ vtb,
    unsigned short* __restrict__ pb)
{
  __shared__ unsigned short Alds[2][128 * 64];  // [m][g] swizzled
  __shared__ unsigned short Blds[2][80 * 64];   // [col][g] swizzled
  const int tid = threadIdx.x, lane = tid & 63, wid = tid >> 6;
  const int l15 = lane & 15, l4 = lane >> 4;
  const int kc = blockIdx.x, nq = blockIdx.y;
  const int g0 = kc * 256;
  const int m0 = wid * 16;

  f32x4 acc[5] = {};

  auto stage = [&](int b, int st) {             // 3 GLL/thread (+1 for tid<128)
    const int gs = g0 + st * 64;
    #pragma unroll
    for (int p = 0; p < 2; ++p) {
      const int e = p * 512 + tid;
      const int row = e >> 3;
      const int cs = (e & 7) ^ (row & 7);
      GLL(qtb + (size_t)row * 8192 + gs + cs * 8, &Alds[b][(p * 512 + (tid & ~63)) * 8]);
    }
    {
      const int row = tid >> 3;
      const int cglob = nq * 80 + row;
      const unsigned short* src = (cglob < 128) ? (qtb + (size_t)cglob * 8192)
                                                : (vtb + (size_t)(cglob - 128) * 8192);
      const int cs = (tid & 7) ^ (row & 7);
      GLL(src + gs + cs * 8, &Blds[b][(tid & ~63) * 8]);
    }
    if (tid < 128) {
      const int e = 512 + tid;
      const int row = e >> 3;
      const int cglob = nq * 80 + row;
      const unsigned short* src = (cglob < 128) ? (qtb + (size_t)cglob * 8192)
                                                : (vtb + (size_t)(cglob - 128) * 8192);
      const int cs = (e & 7) ^ (row & 7);
      GLL(src + gs + cs * 8, &Blds[b][(512 + (tid & ~63)) * 8]);
    }
  };

  stage(0, 0);
  stage(1, 1);

  for (int st = 0; st < 4; ++st) {
    const int cur = st & 1;
    if (st < 3) { WAITV(3); } else { WAITV(0); }  // waves w/ 4 loads over-wait by 1: safe
    RBAR();
    SFENCE();
    #pragma unroll
    for (int ks = 0; ks < 2; ++ks) {
      const int ra = m0 + l15;
      const int ca = ks * 4 + l4;
      const bf16x8 af = *(const bf16x8*)(&Alds[cur][ra * 64 + ((ca ^ (ra & 7)) * 8)]);
      #pragma unroll
      for (int nf = 0; nf < 5; ++nf) {
        const int rb = nf * 16 + l15;
        const bf16x8 bf = *(const bf16x8*)(&Blds[cur][rb * 64 + ((ca ^ (rb & 7)) * 8)]);
        acc[nf] = __builtin_amdgcn_mfma_f32_16x16x32_bf16(af, bf, acc[nf], 0, 0, 0);
      }
    }
    SFENCE();
    RBAR();
    if (st < 2) stage(cur, st + 2);
  }

  #pragma unroll
  for (int nf = 0; nf < 5; ++nf) {
    const int col = nq * 80 + nf * 16 + l15;
    #pragma unroll
    for (int r = 0; r < 4; ++r) {
      const int row = m0 + l4 * 4 + r;
      pb[((size_t)kc * 128 + row) * 640 + col] = f2bf(acc[nf][r]);
    }
  }
}

// Sum 32 bf16 partials -> Gb [128][128] bf16, Hbt [512][128] bf16 (H transposed).
__global__ void gh_finalize(const unsigned short* __restrict__ pb,
                            unsigned short* __restrict__ Gb, unsigned short* __restrict__ Hbt) {
  const int idx = blockIdx.x * 256 + threadIdx.x;  // 0..81919
  float s = 0.f;
  #pragma unroll
  for (int p = 0; p < 32; ++p) s += bf2f(pb[(size_t)p * 81920 + idx]);
  const int m = idx / 640, c = idx % 640;
  if (c < 128) Gb[m * 128 + c] = f2bf(s);
  else         Hbt[(size_t)(c - 128) * 128 + m] = f2bf(s);
}

// ---------------- fused: rnorm (k_i G k_i^T) + out = (K·H)*rnorm + v ----------------
// grid 512 blocks of 16 rows; 512 thr (8 waves). Barrier deferred until after U-MFMAs.
__global__ __launch_bounds__(512) void tnorm_uv(
    const unsigned short* __restrict__ kb, const unsigned short* __restrict__ Gb,
    const unsigned short* __restrict__ Hbt, const unsigned short* __restrict__ vb,
    float* __restrict__ out)
{
  __shared__ float ssq_part[8][16];
  __shared__ float rnorm_lds[16];
  const int tid = threadIdx.x, lane = tid & 63, wid = tid >> 6;
  const int l15 = lane & 15, l4 = lane >> 4;
  const int rowbase = blockIdx.x * 16;

  // K A-fragments for these 16 rows (shared by both phases)
  bf16x8 af[4];
  #pragma unroll
  for (int ks = 0; ks < 4; ++ks)
    af[ks] = *(const bf16x8*)(kb + (size_t)(rowbase + l15) * 128 + ks * 32 + l4 * 8);

  // ---- phase 1: T-frag (cols wid*16..+16) of T = K·G, partial rowdot ----
  f32x4 tac = {};
  #pragma unroll
  for (int ks = 0; ks < 4; ++ks) {
    const bf16x8 bf = *(const bf16x8*)(Gb + (size_t)(wid * 16 + l15) * 128 + ks * 32 + l4 * 8);
    tac = __builtin_amdgcn_mfma_f32_16x16x32_bf16(af[ks], bf, tac, 0, 0, 0);
  }
  float ssq[4];
  #pragma unroll
  for (int r = 0; r < 4; ++r) {
    const int row = rowbase + l4 * 4 + r;
    ssq[r] = tac[r] * bf2f(kb[(size_t)row * 128 + wid * 16 + l15]);
  }
  #pragma unroll
  for (int d = 1; d < 16; d <<= 1)
    #pragma unroll
    for (int r = 0; r < 4; ++r) ssq[r] += __shfl_xor(ssq[r], d);
  if (l15 == 0) {
    #pragma unroll
    for (int r = 0; r < 4; ++r) ssq_part[wid][l4 * 4 + r] = ssq[r];
  }

  // ---- phase 2 (before barrier): U = K·H for cols [wid*64, +64) ----
  f32x4 acc[4] = {};
  #pragma unroll
  for (int ks = 0; ks < 4; ++ks) {
    #pragma unroll
    for (int nf = 0; nf < 4; ++nf) {
      const int col = wid * 64 + nf * 16 + l15;
      const bf16x8 bf = *(const bf16x8*)(Hbt + (size_t)col * 128 + ks * 32 + l4 * 8);
      acc[nf] = __builtin_amdgcn_mfma_f32_16x16x32_bf16(af[ks], bf, acc[nf], 0, 0, 0);
    }
  }
  // hoist residual loads so they pipeline under the barrier
  float vres[4][4];
  #pragma unroll
  for (int nf = 0; nf < 4; ++nf) {
    const int col = wid * 64 + nf * 16 + l15;
    #pragma unroll
    for (int r = 0; r < 4; ++r)
      vres[nf][r] = bf2f(vb[(size_t)(rowbase + l4 * 4 + r) * 512 + col]);
  }

  __syncthreads();
  if (tid < 16) {
    float s = 0.f;
    #pragma unroll
    for (int w = 0; w < 8; ++w) s += ssq_part[w][tid];
    rnorm_lds[tid] = 1.0f / fmaxf(sqrtf(s), 1e-12f);
  }
  __syncthreads();

  float rn[4];
  #pragma unroll
  for (int r = 0; r < 4; ++r) rn[r] = rnorm_lds[l4 * 4 + r];

  #pragma unroll
  for (int nf = 0; nf < 4; ++nf) {
    const int col = wid * 64 + nf * 16 + l15;
    #pragma unroll
    for (int r = 0; r < 4; ++r) {
      const int row = rowbase + l4 * 4 + r;
      out[(size_t)row * 512 + col] = acc[nf][r] * rn[r] + vres[nf][r];
    }
  }
}

extern "C" void kernel_launch(void* const* d_in, const int* in_sizes, int n_in,
                              void* d_out, int out_size, void* d_ws, size_t ws_size,
                              hipStream_t stream) {
  const float* x  = (const float*)d_in[0];
  const float* Wk = (const float*)d_in[1];
  const float* bk = (const float*)d_in[2];
  const float* Wq = (const float*)d_in[3];
  const float* bq = (const float*)d_in[4];
  const float* Wv = (const float*)d_in[5];
  const float* bv = (const float*)d_in[6];
  float* out = (float*)d_out;

  char* ws = (char*)d_ws;
  unsigned short* xb   = (unsigned short*)(ws);              //  8192*512*2 = 8,388,608
  unsigned short* wb   = (unsigned short*)(ws + 8388608);    //   768*512*2 =   786,432
  unsigned short* kb   = (unsigned short*)(ws + 9175040);    //  8192*128*2 = 2,097,152
  unsigned short* vb   = (unsigned short*)(ws + 11272192);   //  8192*512*2 = 8,388,608
  unsigned short* vtb  = (unsigned short*)(ws + 19660800);   //   512*8192*2= 8,388,608
  unsigned short* qtb  = (unsigned short*)(ws + 28049408);   //   128*8192*2= 2,097,152
  unsigned short* pb   = (unsigned short*)(ws + 30146560);   //  32*128*640*2=5,242,880
  unsigned short* Gb   = (unsigned short*)(ws + 35389440);   //   128*128*2 =    32,768
  unsigned short* Hbt  = (unsigned short*)(ws + 35422208);   //   512*128*2 =   131,072

  cvt_all<<<4480, 256, 0, stream>>>(x, Wk, Wq, Wv, xb, wb);
  qkv_gemm<<<256, 512, 0, stream>>>(xb, wb, bk, bq, bv, kb, qtb, vb, vtb);
  gh_gemm<<<dim3(32, 8), 512, 0, stream>>>(qtb, vtb, pb);
  gh_finalize<<<320, 256, 0, stream>>>(pb, Gb, Hbt);
  tnorm_uv<<<512, 512, 0, stream>>>(kb, Gb, Hbt, vb, out);
}